// Round 1
// baseline (548.759 us; speedup 1.0000x reference)
//
#include <hip/hip_runtime.h>
#include <cstdint>
#include <cstddef>

#define DIM    2048
#define HEADS  16
#define DH     128
#define INNER  2048
#define SEQ    2048
#define BATCH  2
#define NTOK   4096

typedef unsigned short u16;
typedef __attribute__((ext_vector_type(8))) short bf16x8;
typedef __attribute__((ext_vector_type(4))) float f32x4;

__device__ __forceinline__ u16 f2bf(float f) {
  union { float f; unsigned u; } v; v.f = f;
  unsigned r = v.u + 0x7FFFu + ((v.u >> 16) & 1u);
  return (u16)(r >> 16);
}
__device__ __forceinline__ float bf2f(u16 h) {
  union { unsigned u; float f; } v; v.u = ((unsigned)h) << 16;
  return v.f;
}

using as1_t = __attribute__((address_space(1))) const void;
using as3_t = __attribute__((address_space(3))) void;
__device__ __forceinline__ void gload_lds16(const void* g, void* l) {
  __builtin_amdgcn_global_load_lds((as1_t*)g, (as3_t*)l, 16, 0, 0);
}

__device__ __forceinline__ f32x4 mfma16(bf16x8 a, bf16x8 b, f32x4 c) {
  return __builtin_amdgcn_mfma_f32_16x16x32_bf16(a, b, c, 0, 0, 0);
}

// ---------------- weight transpose + cast: W[K][N] f32 -> Wt[N][K] bf16 ----
__global__ __launch_bounds__(256)
void transpose_cast(const float* __restrict__ W, u16* __restrict__ Wt,
                    int K, int N) {
  __shared__ float t[32][33];
  const int tiles_n = N >> 5;
  const int tx = blockIdx.x % tiles_n, ty = blockIdx.x / tiles_n;
  const int tid = threadIdx.x;
  const int k0 = ty << 5, n0 = tx << 5;
  #pragma unroll
  for (int i = 0; i < 4; ++i) {
    int e = tid + i * 256, rr = e >> 5, cc = e & 31;
    t[rr][cc] = W[(size_t)(k0 + rr) * N + n0 + cc];
  }
  __syncthreads();
  #pragma unroll
  for (int i = 0; i < 4; ++i) {
    int e = tid + i * 256, rr = e >> 5, cc = e & 31;
    Wt[(size_t)(n0 + rr) * K + k0 + cc] = f2bf(t[cc][rr]);
  }
}

// ---------------- rope cos/sin tables ----------------
__global__ __launch_bounds__(256)
void build_tables(const float* __restrict__ rot, float* __restrict__ cosT,
                  float* __restrict__ sinT) {
  int i = blockIdx.x * 256 + threadIdx.x;
  float v = rot[i];
  cosT[i] = cosf(v);
  sinT[i] = sinf(v);
}

// ---------------- RMSNorm: x f32 [NTOK][DIM] -> xn bf16 ----------------
__global__ __launch_bounds__(256)
void rmsnorm_k(const float* __restrict__ x, const float* __restrict__ gw,
               u16* __restrict__ xn) {
  const int row = blockIdx.x, tid = threadIdx.x;
  const float4* x4 = (const float4*)(x + (size_t)row * DIM);
  float4 a = x4[tid * 2], b = x4[tid * 2 + 1];
  float ss = a.x*a.x + a.y*a.y + a.z*a.z + a.w*a.w
           + b.x*b.x + b.y*b.y + b.z*b.z + b.w*b.w;
  #pragma unroll
  for (int off = 1; off < 64; off <<= 1) ss += __shfl_xor(ss, off);
  __shared__ float red[4];
  if ((tid & 63) == 0) red[tid >> 6] = ss;
  __syncthreads();
  float tot = red[0] + red[1] + red[2] + red[3];
  float sc = 1.0f / fmaxf(sqrtf(tot * (1.0f / DIM)), 1e-8f);
  const float4* g4 = (const float4*)gw;
  float4 ga = g4[tid * 2], gb = g4[tid * 2 + 1];
  u16 ov[8];
  ov[0] = f2bf(a.x * sc * ga.x); ov[1] = f2bf(a.y * sc * ga.y);
  ov[2] = f2bf(a.z * sc * ga.z); ov[3] = f2bf(a.w * sc * ga.w);
  ov[4] = f2bf(b.x * sc * gb.x); ov[5] = f2bf(b.y * sc * gb.y);
  ov[6] = f2bf(b.z * sc * gb.z); ov[7] = f2bf(b.w * sc * gb.w);
  *(uint4*)(xn + (size_t)row * DIM + tid * 8) = *(const uint4*)ov;
}

// ---------------- GEMM: C[M][N] = A[M][K] * Bt[N][K]^T (bf16 in, f32 acc) --
// 128x128 tile, BK=32, 4 waves (2x2), double-buffered LDS via global_load_lds.
// LDS tiles [128][32] bf16, 64B rows; XOR swizzle byte^=(((row>>1)&3)<<4).
template<int F32OUT>
__global__ __launch_bounds__(256)
void gemm_bt(const u16* __restrict__ A, const u16* __restrict__ Bt,
             void* __restrict__ C, int M, int N, int K) {
  const int tid = threadIdx.x;
  const int wave = tid >> 6, lane = tid & 63;
  const int mt = blockIdx.y, nt0 = blockIdx.x;
  __shared__ __align__(16) u16 ldsA[2][128 * 32];
  __shared__ __align__(16) u16 ldsB[2][128 * 32];

  const int wm = (wave >> 1) * 64, wn = (wave & 1) * 64;
  const int r = lane & 15, g = lane >> 4;

  f32x4 acc[4][4];
  const f32x4 z4 = {0.f, 0.f, 0.f, 0.f};
  #pragma unroll
  for (int i = 0; i < 4; ++i)
    #pragma unroll
    for (int j = 0; j < 4; ++j) acc[i][j] = z4;

  const u16* Abase = A + (size_t)mt * 128 * K;
  const u16* Bbase = Bt + (size_t)nt0 * 128 * K;

  auto stage = [&](u16* dst, const u16* src, int kb) {
    #pragma unroll
    for (int c = 0; c < 2; ++c) {
      int chunk = wave * 128 + c * 64 + lane;
      int row = chunk >> 2;
      int colb = (chunk & 3) << 4;
      int scolb = colb ^ (((row >> 1) & 3) << 4);
      gload_lds16(src + (size_t)row * K + kb + (scolb >> 1),
                  dst + (wave * 128 + c * 64) * 8);
    }
  };

  const int nk = K >> 5;
  stage(ldsA[0], Abase, 0);
  stage(ldsB[0], Bbase, 0);
  __syncthreads();

  for (int kt = 0; kt < nk; ++kt) {
    const int cur = kt & 1;
    if (kt + 1 < nk) {
      stage(ldsA[cur ^ 1], Abase, (kt + 1) << 5);
      stage(ldsB[cur ^ 1], Bbase, (kt + 1) << 5);
    }
    bf16x8 af[4], bfr[4];
    #pragma unroll
    for (int mi = 0; mi < 4; ++mi) {
      int row = wm + mi * 16 + r;
      int off = row * 32 + (((g << 4) ^ (((row >> 1) & 3) << 4)) >> 1);
      af[mi] = *(const bf16x8*)&ldsA[cur][off];
    }
    #pragma unroll
    for (int ni = 0; ni < 4; ++ni) {
      int row = wn + ni * 16 + r;
      int off = row * 32 + (((g << 4) ^ (((row >> 1) & 3) << 4)) >> 1);
      bfr[ni] = *(const bf16x8*)&ldsB[cur][off];
    }
    #pragma unroll
    for (int mi = 0; mi < 4; ++mi)
      #pragma unroll
      for (int ni = 0; ni < 4; ++ni)
        acc[mi][ni] = mfma16(af[mi], bfr[ni], acc[mi][ni]);
    __syncthreads();
  }

  #pragma unroll
  for (int mi = 0; mi < 4; ++mi)
    #pragma unroll
    for (int ni = 0; ni < 4; ++ni)
      #pragma unroll
      for (int rr = 0; rr < 4; ++rr) {
        int row = mt * 128 + wm + mi * 16 + g * 4 + rr;
        int col = nt0 * 128 + wn + ni * 16 + r;
        float v = acc[mi][ni][rr];
        if (F32OUT) ((float*)C)[(size_t)row * N + col] = v;
        else        ((u16*)C)[(size_t)row * N + col] = f2bf(v);
      }
}

// ---------------- RoPE + rearrange: src[NTOK][ldsrc] -> dst[B][H][SEQ][DH] --
__global__ __launch_bounds__(256)
void rope_rearrange(const u16* __restrict__ src, int ldsrc,
                    const float* __restrict__ cosT, const float* __restrict__ sinT,
                    u16* __restrict__ dst, float scale) {
  int id = blockIdx.x * 256 + threadIdx.x;
  int d2 = id & 63;
  int hh = (id >> 6) & 15;
  int tok = id >> 10;
  int n = tok & (SEQ - 1);
  int b = tok >> 11;
  const u16* s = src + (size_t)tok * ldsrc + hh * DH;
  float t1 = bf2f(s[d2]), t2 = bf2f(s[d2 + 64]);
  float c1 = cosT[n * DH + d2], c2 = cosT[n * DH + d2 + 64];
  float s1 = sinT[n * DH + d2], s2 = sinT[n * DH + d2 + 64];
  u16* dp = dst + ((size_t)(b * HEADS + hh) * SEQ + n) * DH;
  dp[d2]      = f2bf((t1 * c1 - t2 * s1) * scale);
  dp[d2 + 64] = f2bf((t2 * c2 + t1 * s2) * scale);
}

// ---------------- V transpose: kv[NTOK][2*INNER] (v half) -> vT[B][H][DH][SEQ]
__global__ __launch_bounds__(256)
void transp_v(const u16* __restrict__ kv, u16* __restrict__ vTo) {
  __shared__ __align__(16) u16 t[32][136];
  const int id = blockIdx.x;
  const int ntile = id & 63;
  const int hh = (id >> 6) & 15;
  const int b = id >> 10;
  const int tid = threadIdx.x;
  const int n0 = ntile * 32;
  #pragma unroll
  for (int it = 0; it < 2; ++it) {
    int chunk = it * 256 + tid;
    int nr = chunk >> 4, dc = chunk & 15;
    const u16* src = kv + (size_t)(b * SEQ + n0 + nr) * (2 * INNER) + INNER + hh * DH + dc * 8;
    *(uint4*)&t[nr][dc * 8] = *(const uint4*)src;
  }
  __syncthreads();
  int d = tid >> 1, nh = tid & 1;
  u16 tmp[16];
  #pragma unroll
  for (int j = 0; j < 16; ++j) tmp[j] = t[nh * 16 + j][d];
  u16* dst = vTo + ((size_t)(b * HEADS + hh) * DH + d) * SEQ + n0 + nh * 16;
  *(uint4*)&dst[0] = *(const uint4*)&tmp[0];
  *(uint4*)&dst[8] = *(const uint4*)&tmp[8];
}

// ---------------- flash attention (causal) ----------------
// 4 waves x 16 q-rows, KVBLK=64. K tile [64][128] + V tile [128][64] in LDS,
// XOR-swizzled; per-wave P buffer [16][64] swizzled both sides.
__global__ __launch_bounds__(256)
void flash(const u16* __restrict__ qr, const u16* __restrict__ kr,
           const u16* __restrict__ vT, u16* __restrict__ attn) {
  const int qt = blockIdx.x, h = blockIdx.y, b = blockIdx.z;
  const int tid = threadIdx.x, wave = tid >> 6, lane = tid & 63;
  const int r = lane & 15, g = lane >> 4;

  __shared__ __align__(16) u16 kT[64 * 128];
  __shared__ __align__(16) u16 vS[128 * 64];
  __shared__ __align__(16) u16 pS[4][16 * 64];

  const size_t headq = (size_t)(b * HEADS + h) * SEQ;
  const u16* qbase = qr + (headq + qt * 64 + wave * 16) * DH;
  const u16* kbase = kr + headq * DH;
  const u16* vbase = vT + (size_t)(b * HEADS + h) * DH * SEQ;

  bf16x8 qf[4];
  #pragma unroll
  for (int ks = 0; ks < 4; ++ks)
    qf[ks] = *(const bf16x8*)(qbase + r * DH + ks * 32 + g * 8);

  const f32x4 z4 = {0.f, 0.f, 0.f, 0.f};
  f32x4 o[8];
  #pragma unroll
  for (int i = 0; i < 8; ++i) o[i] = z4;
  float m[4], lsum[4];
  #pragma unroll
  for (int i = 0; i < 4; ++i) { m[i] = -3.0e38f; lsum[i] = 0.f; }

  const int nkv = qt + 1;
  for (int kt = 0; kt < nkv; ++kt) {
    __syncthreads();
    #pragma unroll
    for (int c = 0; c < 4; ++c) {   // stage K [64 rows][128 d]
      int chunk = (wave * 4 + c) * 64 + lane;
      int row = chunk >> 4;
      int colb = (chunk & 15) << 4;
      int scolb = colb ^ ((row & 7) << 4);
      gload_lds16(kbase + (size_t)(kt * 64 + row) * DH + (scolb >> 1),
                  kT + (wave * 4 + c) * 64 * 8);
    }
    #pragma unroll
    for (int c = 0; c < 4; ++c) {   // stage V [128 d][64 kv]
      int chunk = (wave * 4 + c) * 64 + lane;
      int d = chunk >> 3;
      int slotb = (chunk & 7) << 4;
      int sb = slotb ^ ((d & 7) << 4);
      gload_lds16(vbase + (size_t)d * SEQ + kt * 64 + (sb >> 1),
                  vS + (wave * 4 + c) * 64 * 8);
    }
    __syncthreads();

    // S = q k^T  (per wave: 16 rows x 64 cols)
    f32x4 s[4];
    #pragma unroll
    for (int i = 0; i < 4; ++i) s[i] = z4;
    #pragma unroll
    for (int ks = 0; ks < 4; ++ks) {
      #pragma unroll
      for (int nt = 0; nt < 4; ++nt) {
        int row = nt * 16 + r;
        int off = row * 128 + (((ks * 64 + g * 16) ^ ((row & 7) << 4)) >> 1);
        bf16x8 kf = *(const bf16x8*)&kT[off];
        s[nt] = mfma16(qf[ks], kf, s[nt]);
      }
    }

    if (kt == qt) {                  // causal mask on diagonal tile
      #pragma unroll
      for (int nt = 0; nt < 4; ++nt)
        #pragma unroll
        for (int rr = 0; rr < 4; ++rr) {
          int colg = kt * 64 + nt * 16 + r;
          int rowg = qt * 64 + wave * 16 + g * 4 + rr;
          if (colg > rowg) s[nt][rr] = -1e30f;
        }
    }

    float mnew[4], alpha[4], rs[4];
    #pragma unroll
    for (int rr = 0; rr < 4; ++rr) {
      float mx = fmaxf(fmaxf(s[0][rr], s[1][rr]), fmaxf(s[2][rr], s[3][rr]));
      #pragma unroll
      for (int off = 1; off < 16; off <<= 1)
        mx = fmaxf(mx, __shfl_xor(mx, off));
      mnew[rr] = fmaxf(m[rr], mx);
      alpha[rr] = __expf(m[rr] - mnew[rr]);
      m[rr] = mnew[rr];
      rs[rr] = 0.f;
    }
    #pragma unroll
    for (int nt = 0; nt < 4; ++nt)
      #pragma unroll
      for (int rr = 0; rr < 4; ++rr) {
        float p = __expf(s[nt][rr] - mnew[rr]);
        rs[rr] += p;
        int prow = g * 4 + rr;
        int colb = (nt * 16 + r) << 1;
        int off = prow * 64 + ((colb ^ ((prow & 7) << 4)) >> 1);
        pS[wave][off] = f2bf(p);
      }
    #pragma unroll
    for (int rr = 0; rr < 4; ++rr) {
      float tsum = rs[rr];
      #pragma unroll
      for (int off = 1; off < 16; off <<= 1) tsum += __shfl_xor(tsum, off);
      lsum[rr] = lsum[rr] * alpha[rr] + tsum;
    }
    #pragma unroll
    for (int dt = 0; dt < 8; ++dt)
      #pragma unroll
      for (int rr = 0; rr < 4; ++rr)
        o[dt][rr] *= alpha[rr];

    // O += P @ V
    #pragma unroll
    for (int ks = 0; ks < 2; ++ks) {
      int poff = r * 64 + (((ks * 64 + g * 16) ^ ((r & 7) << 4)) >> 1);
      bf16x8 pf = *(const bf16x8*)&pS[wave][poff];
      #pragma unroll
      for (int dt = 0; dt < 8; ++dt) {
        int vrow = dt * 16 + r;
        int voff = vrow * 64 + (((ks * 64 + g * 16) ^ ((vrow & 7) << 4)) >> 1);
        bf16x8 vf = *(const bf16x8*)&vS[voff];
        o[dt] = mfma16(pf, vf, o[dt]);
      }
    }
  }

  #pragma unroll
  for (int dt = 0; dt < 8; ++dt)
    #pragma unroll
    for (int rr = 0; rr < 4; ++rr) {
      int rowg = qt * 64 + wave * 16 + g * 4 + rr;
      attn[((size_t)b * SEQ + rowg) * INNER + h * DH + dt * 16 + r] =
          f2bf(o[dt][rr] / lsum[rr]);
    }
}

// ---------------- host ----------------
extern "C" void kernel_launch(void* const* d_in, const int* in_sizes, int n_in,
                              void* d_out, int out_size, void* d_ws, size_t ws_size,
                              hipStream_t stream) {
  const float* x   = (const float*)d_in[0];
  const float* rot = (const float*)d_in[1];
  const float* g   = (const float*)d_in[2];
  const float* Wq  = (const float*)d_in[3];
  const float* Wkv = (const float*)d_in[4];
  const float* Wo  = (const float*)d_in[5];

  char* ws = (char*)d_ws;
  size_t off = 0;
  auto alloc = [&](size_t bytes) {
    char* p = ws + off;
    off += (bytes + 255) & ~(size_t)255;
    return p;
  };
  u16*   WqT  = (u16*)alloc((size_t)2048 * 2048 * 2);
  u16*   WkvT = (u16*)alloc((size_t)4096 * 2048 * 2);
  u16*   WoT  = (u16*)alloc((size_t)2048 * 2048 * 2);
  float* cosT = (float*)alloc((size_t)2048 * 128 * 4);
  float* sinT = (float*)alloc((size_t)2048 * 128 * 4);
  u16*   xn   = (u16*)alloc((size_t)4096 * 2048 * 2);
  u16*   q    = (u16*)alloc((size_t)4096 * 2048 * 2);
  u16*   kv   = (u16*)alloc((size_t)4096 * 4096 * 2);
  // region reuse (dependency-checked against launch order below):
  u16* qr   = WkvT;  // WkvT dead after KV GEMM
  u16* kr   = q;     // q dead after rope_q
  u16* vt   = xn;    // xn dead after both GEMMs
  u16* attn = kv;    // kv dead after rope_k + transp_v

  transpose_cast<<<dim3(64 * 64),  256, 0, stream>>>(Wq,  WqT,  2048, 2048);
  transpose_cast<<<dim3(64 * 128), 256, 0, stream>>>(Wkv, WkvT, 2048, 4096);
  transpose_cast<<<dim3(64 * 64),  256, 0, stream>>>(Wo,  WoT,  2048, 2048);
  build_tables<<<dim3(2048 * 128 / 256), 256, 0, stream>>>(rot, cosT, sinT);
  rmsnorm_k<<<dim3(4096), 256, 0, stream>>>(x, g, xn);
  gemm_bt<0><<<dim3(16, 32), 256, 0, stream>>>(xn, WqT,  q,  4096, 2048, 2048);
  gemm_bt<0><<<dim3(32, 32), 256, 0, stream>>>(xn, WkvT, kv, 4096, 4096, 2048);
  rope_rearrange<<<dim3(16384), 256, 0, stream>>>(q,  INNER,     cosT, sinT, qr, 0.08838834764831845f);
  rope_rearrange<<<dim3(16384), 256, 0, stream>>>(kv, 2 * INNER, cosT, sinT, kr, 1.0f);
  transp_v<<<dim3(2048), 256, 0, stream>>>(kv, vt);
  flash<<<dim3(32, 16, 2), 256, 0, stream>>>(qr, kr, vt, attn);
  gemm_bt<1><<<dim3(16, 32), 256, 0, stream>>>(attn, WoT, (float*)d_out, 4096, 2048, 2048);
}

// Round 2
// 332.788 us; speedup vs baseline: 1.6490x; 1.6490x over previous
//
#include <hip/hip_runtime.h>
#include <cstdint>
#include <cstddef>

#define DIM    2048
#define HEADS  16
#define DH     128
#define INNER  2048
#define SEQ    2048
#define BATCH  2
#define NTOK   4096

typedef unsigned short u16;
typedef __attribute__((ext_vector_type(8))) short bf16x8;
typedef __attribute__((ext_vector_type(4))) float f32x4;

__device__ __forceinline__ u16 f2bf(float f) {
  union { float f; unsigned u; } v; v.f = f;
  unsigned r = v.u + 0x7FFFu + ((v.u >> 16) & 1u);
  return (u16)(r >> 16);
}
__device__ __forceinline__ float bf2f(u16 h) {
  union { unsigned u; float f; } v; v.u = ((unsigned)h) << 16;
  return v.f;
}

using as1_t = __attribute__((address_space(1))) const void;
using as3_t = __attribute__((address_space(3))) void;
__device__ __forceinline__ void gload_lds16(const void* g, void* l) {
  __builtin_amdgcn_global_load_lds((as1_t*)g, (as3_t*)l, 16, 0, 0);
}

__device__ __forceinline__ f32x4 mfma16(bf16x8 a, bf16x8 b, f32x4 c) {
  return __builtin_amdgcn_mfma_f32_16x16x32_bf16(a, b, c, 0, 0, 0);
}

// ---------------- weight transpose + cast: W[K][N] f32 -> Wt[N][K] bf16 ----
__global__ __launch_bounds__(256)
void transpose_cast(const float* __restrict__ W, u16* __restrict__ Wt,
                    int K, int N) {
  __shared__ float t[32][33];
  const int tiles_n = N >> 5;
  const int tx = blockIdx.x % tiles_n, ty = blockIdx.x / tiles_n;
  const int tid = threadIdx.x;
  const int k0 = ty << 5, n0 = tx << 5;
  #pragma unroll
  for (int i = 0; i < 4; ++i) {
    int e = tid + i * 256, rr = e >> 5, cc = e & 31;
    t[rr][cc] = W[(size_t)(k0 + rr) * N + n0 + cc];
  }
  __syncthreads();
  #pragma unroll
  for (int i = 0; i < 4; ++i) {
    int e = tid + i * 256, rr = e >> 5, cc = e & 31;
    Wt[(size_t)(n0 + rr) * K + k0 + cc] = f2bf(t[cc][rr]);
  }
}

// ---------------- rope cos/sin tables ----------------
__global__ __launch_bounds__(256)
void build_tables(const float* __restrict__ rot, float* __restrict__ cosT,
                  float* __restrict__ sinT) {
  int i = blockIdx.x * 256 + threadIdx.x;
  float v = rot[i];
  cosT[i] = cosf(v);
  sinT[i] = sinf(v);
}

// ---------------- RMSNorm: x f32 [NTOK][DIM] -> xn bf16 ----------------
__global__ __launch_bounds__(256)
void rmsnorm_k(const float* __restrict__ x, const float* __restrict__ gw,
               u16* __restrict__ xn) {
  const int row = blockIdx.x, tid = threadIdx.x;
  const float4* x4 = (const float4*)(x + (size_t)row * DIM);
  float4 a = x4[tid * 2], b = x4[tid * 2 + 1];
  float ss = a.x*a.x + a.y*a.y + a.z*a.z + a.w*a.w
           + b.x*b.x + b.y*b.y + b.z*b.z + b.w*b.w;
  #pragma unroll
  for (int off = 1; off < 64; off <<= 1) ss += __shfl_xor(ss, off);
  __shared__ float red[4];
  if ((tid & 63) == 0) red[tid >> 6] = ss;
  __syncthreads();
  float tot = red[0] + red[1] + red[2] + red[3];
  float sc = 1.0f / fmaxf(sqrtf(tot * (1.0f / DIM)), 1e-8f);
  const float4* g4 = (const float4*)gw;
  float4 ga = g4[tid * 2], gb = g4[tid * 2 + 1];
  u16 ov[8];
  ov[0] = f2bf(a.x * sc * ga.x); ov[1] = f2bf(a.y * sc * ga.y);
  ov[2] = f2bf(a.z * sc * ga.z); ov[3] = f2bf(a.w * sc * ga.w);
  ov[4] = f2bf(b.x * sc * gb.x); ov[5] = f2bf(b.y * sc * gb.y);
  ov[6] = f2bf(b.z * sc * gb.z); ov[7] = f2bf(b.w * sc * gb.w);
  *(uint4*)(xn + (size_t)row * DIM + tid * 8) = *(const uint4*)ov;
}

// ---------------- GEMM: C[M][N] = A[M][K] * Bt[N][K]^T (bf16 in, f32 acc) --
template<int F32OUT>
__global__ __launch_bounds__(256)
void gemm_bt(const u16* __restrict__ A, const u16* __restrict__ Bt,
             void* __restrict__ C, int M, int N, int K) {
  const int tid = threadIdx.x;
  const int wave = tid >> 6, lane = tid & 63;
  const int mt = blockIdx.y, nt0 = blockIdx.x;
  __shared__ __align__(16) u16 ldsA[2][128 * 32];
  __shared__ __align__(16) u16 ldsB[2][128 * 32];

  const int wm = (wave >> 1) * 64, wn = (wave & 1) * 64;
  const int r = lane & 15, g = lane >> 4;

  f32x4 acc[4][4];
  const f32x4 z4 = {0.f, 0.f, 0.f, 0.f};
  #pragma unroll
  for (int i = 0; i < 4; ++i)
    #pragma unroll
    for (int j = 0; j < 4; ++j) acc[i][j] = z4;

  const u16* Abase = A + (size_t)mt * 128 * K;
  const u16* Bbase = Bt + (size_t)nt0 * 128 * K;

  auto stage = [&](u16* dst, const u16* src, int kb) {
    #pragma unroll
    for (int c = 0; c < 2; ++c) {
      int chunk = wave * 128 + c * 64 + lane;
      int row = chunk >> 2;
      int colb = (chunk & 3) << 4;
      int scolb = colb ^ (((row >> 1) & 3) << 4);
      gload_lds16(src + (size_t)row * K + kb + (scolb >> 1),
                  dst + (wave * 128 + c * 64) * 8);
    }
  };

  const int nk = K >> 5;
  stage(ldsA[0], Abase, 0);
  stage(ldsB[0], Bbase, 0);
  __syncthreads();

  for (int kt = 0; kt < nk; ++kt) {
    const int cur = kt & 1;
    if (kt + 1 < nk) {
      stage(ldsA[cur ^ 1], Abase, (kt + 1) << 5);
      stage(ldsB[cur ^ 1], Bbase, (kt + 1) << 5);
    }
    bf16x8 af[4], bfr[4];
    #pragma unroll
    for (int mi = 0; mi < 4; ++mi) {
      int row = wm + mi * 16 + r;
      int off = row * 32 + (((g << 4) ^ (((row >> 1) & 3) << 4)) >> 1);
      af[mi] = *(const bf16x8*)&ldsA[cur][off];
    }
    #pragma unroll
    for (int ni = 0; ni < 4; ++ni) {
      int row = wn + ni * 16 + r;
      int off = row * 32 + (((g << 4) ^ (((row >> 1) & 3) << 4)) >> 1);
      bfr[ni] = *(const bf16x8*)&ldsB[cur][off];
    }
    #pragma unroll
    for (int mi = 0; mi < 4; ++mi)
      #pragma unroll
      for (int ni = 0; ni < 4; ++ni)
        acc[mi][ni] = mfma16(af[mi], bfr[ni], acc[mi][ni]);
    __syncthreads();
  }

  #pragma unroll
  for (int mi = 0; mi < 4; ++mi)
    #pragma unroll
    for (int ni = 0; ni < 4; ++ni)
      #pragma unroll
      for (int rr = 0; rr < 4; ++rr) {
        int row = mt * 128 + wm + mi * 16 + g * 4 + rr;
        int col = nt0 * 128 + wn + ni * 16 + r;
        float v = acc[mi][ni][rr];
        if (F32OUT) ((float*)C)[(size_t)row * N + col] = v;
        else        ((u16*)C)[(size_t)row * N + col] = f2bf(v);
      }
}

// ---------------- RoPE + rearrange: src[NTOK][ldsrc] -> dst[B][H][SEQ][DH] --
__global__ __launch_bounds__(256)
void rope_rearrange(const u16* __restrict__ src, int ldsrc,
                    const float* __restrict__ cosT, const float* __restrict__ sinT,
                    u16* __restrict__ dst, float scale) {
  int id = blockIdx.x * 256 + threadIdx.x;
  int d2 = id & 63;
  int hh = (id >> 6) & 15;
  int tok = id >> 10;
  int n = tok & (SEQ - 1);
  int b = tok >> 11;
  const u16* s = src + (size_t)tok * ldsrc + hh * DH;
  float t1 = bf2f(s[d2]), t2 = bf2f(s[d2 + 64]);
  float c1 = cosT[n * DH + d2], c2 = cosT[n * DH + d2 + 64];
  float s1 = sinT[n * DH + d2], s2 = sinT[n * DH + d2 + 64];
  u16* dp = dst + ((size_t)(b * HEADS + hh) * SEQ + n) * DH;
  dp[d2]      = f2bf((t1 * c1 - t2 * s1) * scale);
  dp[d2 + 64] = f2bf((t2 * c2 + t1 * s2) * scale);
}

// ---------------- V transpose: kv[NTOK][2*INNER] (v half) -> vT[B][H][DH][SEQ]
__global__ __launch_bounds__(256)
void transp_v(const u16* __restrict__ kv, u16* __restrict__ vTo) {
  __shared__ __align__(16) u16 t[32][136];
  const int id = blockIdx.x;
  const int ntile = id & 63;
  const int hh = (id >> 6) & 15;
  const int b = id >> 10;
  const int tid = threadIdx.x;
  const int n0 = ntile * 32;
  #pragma unroll
  for (int it = 0; it < 2; ++it) {
    int chunk = it * 256 + tid;
    int nr = chunk >> 4, dc = chunk & 15;
    const u16* src = kv + (size_t)(b * SEQ + n0 + nr) * (2 * INNER) + INNER + hh * DH + dc * 8;
    *(uint4*)&t[nr][dc * 8] = *(const uint4*)src;
  }
  __syncthreads();
  int d = tid >> 1, nh = tid & 1;
  u16 tmp[16];
  #pragma unroll
  for (int j = 0; j < 16; ++j) tmp[j] = t[nh * 16 + j][d];
  u16* dst = vTo + ((size_t)(b * HEADS + hh) * DH + d) * SEQ + n0 + nh * 16;
  *(uint4*)&dst[0] = *(const uint4*)&tmp[0];
  *(uint4*)&dst[8] = *(const uint4*)&tmp[8];
}

// ---------------- flash attention (causal), pair-balanced + double-buffered -
// grid (hb=32, pair=16). Block handles q-tiles {pair, 31-pair}: 33 kv-iters
// uniform. K/V double-buffered (72 KB LDS, 2 blocks/CU). blockIdx.x = hb so
// all 16 blocks of one head land on one XCD (K/V stays in its L2).
__global__ __launch_bounds__(256)
void flash(const u16* __restrict__ qr, const u16* __restrict__ kr,
           const u16* __restrict__ vT, u16* __restrict__ attn) {
  const int hb = blockIdx.x;
  const int h = hb & 15, b = hb >> 4;
  const int pairi = blockIdx.y;
  const int tid = threadIdx.x, wave = tid >> 6, lane = tid & 63;
  const int r = lane & 15, g = lane >> 4;

  __shared__ __align__(16) u16 kT[2][64 * 128];
  __shared__ __align__(16) u16 vS[2][128 * 64];
  __shared__ __align__(16) u16 pS[4][16 * 64];

  const size_t headq = (size_t)(b * HEADS + h) * SEQ;
  const u16* kbase = kr + headq * DH;
  const u16* vbase = vT + (size_t)(b * HEADS + h) * DH * SEQ;

  auto stageKV = [&](int buf, int kt) {
    #pragma unroll
    for (int c = 0; c < 4; ++c) {   // K [64 rows][128 d], swizzled
      int chunk = (wave * 4 + c) * 64 + lane;
      int row = chunk >> 4;
      int scolb = ((chunk & 15) << 4) ^ ((row & 7) << 4);
      gload_lds16(kbase + (size_t)(kt * 64 + row) * DH + (scolb >> 1),
                  kT[buf] + (wave * 4 + c) * 64 * 8);
    }
    #pragma unroll
    for (int c = 0; c < 4; ++c) {   // V [128 d][64 kv], swizzled
      int chunk = (wave * 4 + c) * 64 + lane;
      int d = chunk >> 3;
      int sb = ((chunk & 7) << 4) ^ ((d & 7) << 4);
      gload_lds16(vbase + (size_t)d * SEQ + kt * 64 + (sb >> 1),
                  vS[buf] + (wave * 4 + c) * 64 * 8);
    }
  };

  const f32x4 z4 = {0.f, 0.f, 0.f, 0.f};

  #pragma unroll 1
  for (int pass = 0; pass < 2; ++pass) {
    const int qt = pass ? (31 - pairi) : pairi;
    const u16* qbase = qr + (headq + qt * 64 + wave * 16) * DH;

    bf16x8 qf[4];
    #pragma unroll
    for (int ks = 0; ks < 4; ++ks)
      qf[ks] = *(const bf16x8*)(qbase + r * DH + ks * 32 + g * 8);

    f32x4 o[8];
    #pragma unroll
    for (int i = 0; i < 8; ++i) o[i] = z4;
    float m[4], lsum[4];
    #pragma unroll
    for (int i = 0; i < 4; ++i) { m[i] = -3.0e38f; lsum[i] = 0.f; }

    const int nkv = qt + 1;
    stageKV(0, 0);
    __syncthreads();

    for (int kt = 0; kt < nkv; ++kt) {
      const int cur = kt & 1;
      if (kt + 1 < nkv) stageKV(cur ^ 1, kt + 1);   // prefetch overlaps compute

      // S = q k^T  (per wave: 16 rows x 64 cols)
      f32x4 s[4];
      #pragma unroll
      for (int i = 0; i < 4; ++i) s[i] = z4;
      #pragma unroll
      for (int ks = 0; ks < 4; ++ks) {
        #pragma unroll
        for (int nt = 0; nt < 4; ++nt) {
          int row = nt * 16 + r;
          int off = row * 128 + (((ks * 64 + g * 16) ^ ((row & 7) << 4)) >> 1);
          bf16x8 kf = *(const bf16x8*)&kT[cur][off];
          s[nt] = mfma16(qf[ks], kf, s[nt]);
        }
      }

      if (kt == qt) {                  // causal mask on diagonal tile
        #pragma unroll
        for (int nt = 0; nt < 4; ++nt)
          #pragma unroll
          for (int rr = 0; rr < 4; ++rr) {
            int colg = nt * 16 + r;
            int rowg = wave * 16 + g * 4 + rr;
            if (colg > rowg) s[nt][rr] = -1e30f;
          }
      }

      float mnew[4], alpha[4], rs[4];
      #pragma unroll
      for (int rr = 0; rr < 4; ++rr) {
        float mx = fmaxf(fmaxf(s[0][rr], s[1][rr]), fmaxf(s[2][rr], s[3][rr]));
        #pragma unroll
        for (int off = 1; off < 16; off <<= 1)
          mx = fmaxf(mx, __shfl_xor(mx, off));
        mnew[rr] = fmaxf(m[rr], mx);
        alpha[rr] = __expf(m[rr] - mnew[rr]);
        m[rr] = mnew[rr];
        rs[rr] = 0.f;
      }
      #pragma unroll
      for (int nt = 0; nt < 4; ++nt)
        #pragma unroll
        for (int rr = 0; rr < 4; ++rr) {
          float p = __expf(s[nt][rr] - mnew[rr]);
          rs[rr] += p;
          int prow = g * 4 + rr;
          int colb = (nt * 16 + r) << 1;
          int off = prow * 64 + ((colb ^ ((prow & 7) << 4)) >> 1);
          pS[wave][off] = f2bf(p);
        }
      #pragma unroll
      for (int rr = 0; rr < 4; ++rr) {
        float tsum = rs[rr];
        #pragma unroll
        for (int off = 1; off < 16; off <<= 1) tsum += __shfl_xor(tsum, off);
        lsum[rr] = lsum[rr] * alpha[rr] + tsum;
      }
      #pragma unroll
      for (int dt = 0; dt < 8; ++dt)
        #pragma unroll
        for (int rr = 0; rr < 4; ++rr)
          o[dt][rr] *= alpha[rr];

      // O += P @ V
      #pragma unroll
      for (int ks = 0; ks < 2; ++ks) {
        int poff = r * 64 + (((ks * 64 + g * 16) ^ ((r & 7) << 4)) >> 1);
        bf16x8 pf = *(const bf16x8*)&pS[wave][poff];
        #pragma unroll
        for (int dt = 0; dt < 8; ++dt) {
          int vrow = dt * 16 + r;
          int voff = vrow * 64 + (((ks * 64 + g * 16) ^ ((vrow & 7) << 4)) >> 1);
          bf16x8 vf = *(const bf16x8*)&vS[cur][voff];
          o[dt] = mfma16(pf, vf, o[dt]);
        }
      }
      __syncthreads();   // drains prefetch; also guards buf reuse next iter
    }

    #pragma unroll
    for (int dt = 0; dt < 8; ++dt)
      #pragma unroll
      for (int rr = 0; rr < 4; ++rr) {
        int rowg = qt * 64 + wave * 16 + g * 4 + rr;
        attn[((size_t)b * SEQ + rowg) * INNER + h * DH + dt * 16 + r] =
            f2bf(o[dt][rr] / lsum[rr]);
      }
  }
}

// ---------------- host ----------------
extern "C" void kernel_launch(void* const* d_in, const int* in_sizes, int n_in,
                              void* d_out, int out_size, void* d_ws, size_t ws_size,
                              hipStream_t stream) {
  const float* x   = (const float*)d_in[0];
  const float* rot = (const float*)d_in[1];
  const float* g   = (const float*)d_in[2];
  const float* Wq  = (const float*)d_in[3];
  const float* Wkv = (const float*)d_in[4];
  const float* Wo  = (const float*)d_in[5];

  char* ws = (char*)d_ws;
  size_t off = 0;
  auto alloc = [&](size_t bytes) {
    char* p = ws + off;
    off += (bytes + 255) & ~(size_t)255;
    return p;
  };
  u16*   WqT  = (u16*)alloc((size_t)2048 * 2048 * 2);
  u16*   WkvT = (u16*)alloc((size_t)4096 * 2048 * 2);
  u16*   WoT  = (u16*)alloc((size_t)2048 * 2048 * 2);
  float* cosT = (float*)alloc((size_t)2048 * 128 * 4);
  float* sinT = (float*)alloc((size_t)2048 * 128 * 4);
  u16*   xn   = (u16*)alloc((size_t)4096 * 2048 * 2);
  u16*   q    = (u16*)alloc((size_t)4096 * 2048 * 2);
  u16*   kv   = (u16*)alloc((size_t)4096 * 4096 * 2);
  // region reuse (dependency-checked against launch order below):
  u16* qr   = WkvT;  // WkvT dead after KV GEMM
  u16* kr   = q;     // q dead after rope_q
  u16* vt   = xn;    // xn dead after both GEMMs
  u16* attn = kv;    // kv dead after rope_k + transp_v

  transpose_cast<<<dim3(64 * 64),  256, 0, stream>>>(Wq,  WqT,  2048, 2048);
  transpose_cast<<<dim3(64 * 128), 256, 0, stream>>>(Wkv, WkvT, 2048, 4096);
  transpose_cast<<<dim3(64 * 64),  256, 0, stream>>>(Wo,  WoT,  2048, 2048);
  build_tables<<<dim3(2048 * 128 / 256), 256, 0, stream>>>(rot, cosT, sinT);
  rmsnorm_k<<<dim3(4096), 256, 0, stream>>>(x, g, xn);
  gemm_bt<0><<<dim3(16, 32), 256, 0, stream>>>(xn, WqT,  q,  4096, 2048, 2048);
  gemm_bt<0><<<dim3(32, 32), 256, 0, stream>>>(xn, WkvT, kv, 4096, 4096, 2048);
  rope_rearrange<<<dim3(16384), 256, 0, stream>>>(q,  INNER,     cosT, sinT, qr, 0.08838834764831845f);
  rope_rearrange<<<dim3(16384), 256, 0, stream>>>(kv, 2 * INNER, cosT, sinT, kr, 1.0f);
  transp_v<<<dim3(2048), 256, 0, stream>>>(kv, vt);
  flash<<<dim3(32, 16), 256, 0, stream>>>(qr, kr, vt, attn);
  gemm_bt<1><<<dim3(16, 32), 256, 0, stream>>>(attn, WoT, (float*)d_out, 4096, 2048, 2048);
}

// Round 3
// 318.883 us; speedup vs baseline: 1.7209x; 1.0436x over previous
//
#include <hip/hip_runtime.h>
#include <cstdint>
#include <cstddef>

#define DIM    2048
#define HEADS  16
#define DH     128
#define INNER  2048
#define SEQ    2048
#define BATCH  2
#define NTOK   4096

typedef unsigned short u16;
typedef __attribute__((ext_vector_type(8))) short bf16x8;
typedef __attribute__((ext_vector_type(4))) float f32x4;

__device__ __forceinline__ u16 f2bf(float f) {
  union { float f; unsigned u; } v; v.f = f;
  unsigned r = v.u + 0x7FFFu + ((v.u >> 16) & 1u);
  return (u16)(r >> 16);
}
__device__ __forceinline__ float bf2f(u16 h) {
  union { unsigned u; float f; } v; v.u = ((unsigned)h) << 16;
  return v.f;
}

using as1_t = __attribute__((address_space(1))) const void;
using as3_t = __attribute__((address_space(3))) void;
__device__ __forceinline__ void gload_lds16(const void* g, void* l) {
  __builtin_amdgcn_global_load_lds((as1_t*)g, (as3_t*)l, 16, 0, 0);
}

__device__ __forceinline__ f32x4 mfma16(bf16x8 a, bf16x8 b, f32x4 c) {
  return __builtin_amdgcn_mfma_f32_16x16x32_bf16(a, b, c, 0, 0, 0);
}

// ---------------- weight transpose + cast: W[K][N] f32 -> Wt[N][K] bf16 ----
__global__ __launch_bounds__(256)
void transpose_cast(const float* __restrict__ W, u16* __restrict__ Wt,
                    int K, int N) {
  __shared__ float t[32][33];
  const int tiles_n = N >> 5;
  const int tx = blockIdx.x % tiles_n, ty = blockIdx.x / tiles_n;
  const int tid = threadIdx.x;
  const int k0 = ty << 5, n0 = tx << 5;
  #pragma unroll
  for (int i = 0; i < 4; ++i) {
    int e = tid + i * 256, rr = e >> 5, cc = e & 31;
    t[rr][cc] = W[(size_t)(k0 + rr) * N + n0 + cc];
  }
  __syncthreads();
  #pragma unroll
  for (int i = 0; i < 4; ++i) {
    int e = tid + i * 256, rr = e >> 5, cc = e & 31;
    Wt[(size_t)(n0 + rr) * K + k0 + cc] = f2bf(t[cc][rr]);
  }
}

// ---------------- rope cos/sin tables ----------------
__global__ __launch_bounds__(256)
void build_tables(const float* __restrict__ rot, float* __restrict__ cosT,
                  float* __restrict__ sinT) {
  int i = blockIdx.x * 256 + threadIdx.x;
  float v = rot[i];
  cosT[i] = cosf(v);
  sinT[i] = sinf(v);
}

// ---------------- RMSNorm: x f32 [NTOK][DIM] -> xn bf16 ----------------
__global__ __launch_bounds__(256)
void rmsnorm_k(const float* __restrict__ x, const float* __restrict__ gw,
               u16* __restrict__ xn) {
  const int row = blockIdx.x, tid = threadIdx.x;
  const float4* x4 = (const float4*)(x + (size_t)row * DIM);
  float4 a = x4[tid * 2], b = x4[tid * 2 + 1];
  float ss = a.x*a.x + a.y*a.y + a.z*a.z + a.w*a.w
           + b.x*b.x + b.y*b.y + b.z*b.z + b.w*b.w;
  #pragma unroll
  for (int off = 1; off < 64; off <<= 1) ss += __shfl_xor(ss, off);
  __shared__ float red[4];
  if ((tid & 63) == 0) red[tid >> 6] = ss;
  __syncthreads();
  float tot = red[0] + red[1] + red[2] + red[3];
  float sc = 1.0f / fmaxf(sqrtf(tot * (1.0f / DIM)), 1e-8f);
  const float4* g4 = (const float4*)gw;
  float4 ga = g4[tid * 2], gb = g4[tid * 2 + 1];
  u16 ov[8];
  ov[0] = f2bf(a.x * sc * ga.x); ov[1] = f2bf(a.y * sc * ga.y);
  ov[2] = f2bf(a.z * sc * ga.z); ov[3] = f2bf(a.w * sc * ga.w);
  ov[4] = f2bf(b.x * sc * gb.x); ov[5] = f2bf(b.y * sc * gb.y);
  ov[6] = f2bf(b.z * sc * gb.z); ov[7] = f2bf(b.w * sc * gb.w);
  *(uint4*)(xn + (size_t)row * DIM + tid * 8) = *(const uint4*)ov;
}

// ---------------- fused QKV GEMM: 256x256 tile, 8-phase-style schedule -----
// C[M=4096][N=6144] = A[4096][2048] * Bt[6144][2048]^T, bf16 in/out, f32 acc.
// 512 threads (8 waves, 2M x 4N; per-wave 128x64). BK=32, 4-slot LDS ring
// (128 KiB). Per K-tile: 2 phases x 16 MFMA; staging runs 3 K-tiles ahead;
// counted s_waitcnt vmcnt(8) once per K-tile (never 0). LDS XOR-swizzled
// (source-pre-swizzled; linear gload_lds dest), read addr col^=(r&3)<<4.
__global__ __launch_bounds__(512, 2)
void gemm_qkv(const u16* __restrict__ A, const u16* __restrict__ Bt,
              u16* __restrict__ C, int M, int N, int K) {
  __shared__ __align__(16) u16 ldsA[4][256 * 32];
  __shared__ __align__(16) u16 ldsB[4][256 * 32];
  const int tid = threadIdx.x;
  const int wave = tid >> 6, lane = tid & 63;
  const int r = lane & 15, g = lane >> 4;
  const int wr = wave >> 2, wc = wave & 3;

  // XCD-aware mapping: grid 384 = 8 XCD-regions x (6 n-tiles x 8 m-tiles)
  const int wgid = blockIdx.x;
  const int xcd = wgid & 7, idx = wgid >> 3;
  const int lm = idx & 7, ln = idx >> 3;
  const int ntile = (xcd & 3) * 6 + ln;
  const int mtile = (xcd >> 2) * 8 + lm;

  const u16* Abase = A + (size_t)mtile * 256 * K;
  const u16* Bbase = Bt + (size_t)ntile * 256 * K;
  const int nk = K >> 5;   // 64 K-tiles

  auto stageA = [&](int jj) {
    int kk = (jj < nk ? jj : nk - 1) * 32;   // clamp keeps vmcnt counting uniform
    #pragma unroll
    for (int c = 0; c < 2; ++c) {
      int chunk = c * 512 + tid;
      int row = chunk >> 2;
      int col = ((chunk & 3) << 3) ^ ((row & 3) << 3);
      gload_lds16(Abase + (size_t)row * K + kk + col,
                  &ldsA[jj & 3][(c * 512 + wave * 64) * 8]);
    }
  };
  auto stageB = [&](int jj) {
    int kk = (jj < nk ? jj : nk - 1) * 32;
    #pragma unroll
    for (int c = 0; c < 2; ++c) {
      int chunk = c * 512 + tid;
      int row = chunk >> 2;
      int col = ((chunk & 3) << 3) ^ ((row & 3) << 3);
      gload_lds16(Bbase + (size_t)row * K + kk + col,
                  &ldsB[jj & 3][(c * 512 + wave * 64) * 8]);
    }
  };

  f32x4 acc[8][4];
  const f32x4 z4 = {0.f, 0.f, 0.f, 0.f};
  #pragma unroll
  for (int i = 0; i < 8; ++i)
    #pragma unroll
    for (int j = 0; j < 4; ++j) acc[i][j] = z4;

  // per-lane LDS read bases (elements); swizzle depends on r only
  const int swz = (g << 3) ^ ((r & 3) << 3);
  const int laneA = (wr * 128 + r) * 32 + swz;
  const int laneB = (wc * 64 + r) * 32 + swz;

  // prologue: stage K-tiles 0,1,2 (12 issues); force K0 (leave newest 8)
  stageA(0); stageB(0); stageA(1); stageB(1); stageA(2); stageB(2);
  asm volatile("s_waitcnt vmcnt(8)" ::: "memory");
  __builtin_amdgcn_s_barrier();

  for (int j = 0; j < nk; ++j) {
    const int buf = j & 3;
    const u16* bufA = &ldsA[buf][0];
    const u16* bufB = &ldsB[buf][0];
    // ---- even phase: read A frags + B ni0,1; stage A_{j+3}
    bf16x8 af[8];
    #pragma unroll
    for (int mi = 0; mi < 8; ++mi)
      af[mi] = *(const bf16x8*)&bufA[laneA + mi * 512];
    bf16x8 bf0 = *(const bf16x8*)&bufB[laneB];
    bf16x8 bf1 = *(const bf16x8*)&bufB[laneB + 512];
    stageA(j + 3);
    __builtin_amdgcn_s_barrier();
    __builtin_amdgcn_s_setprio(1);
    #pragma unroll
    for (int mi = 0; mi < 8; ++mi) {
      acc[mi][0] = mfma16(af[mi], bf0, acc[mi][0]);
      acc[mi][1] = mfma16(af[mi], bf1, acc[mi][1]);
    }
    __builtin_amdgcn_s_setprio(0);
    __builtin_amdgcn_s_barrier();
    // ---- odd phase: read B ni2,3; stage B_{j+3}; force K_{j+1}
    bf16x8 bf2 = *(const bf16x8*)&bufB[laneB + 1024];
    bf16x8 bf3 = *(const bf16x8*)&bufB[laneB + 1536];
    stageB(j + 3);
    asm volatile("s_waitcnt vmcnt(8)" ::: "memory");
    __builtin_amdgcn_s_barrier();
    __builtin_amdgcn_s_setprio(1);
    #pragma unroll
    for (int mi = 0; mi < 8; ++mi) {
      acc[mi][2] = mfma16(af[mi], bf2, acc[mi][2]);
      acc[mi][3] = mfma16(af[mi], bf3, acc[mi][3]);
    }
    __builtin_amdgcn_s_setprio(0);
    __builtin_amdgcn_s_barrier();
  }

  #pragma unroll
  for (int mi = 0; mi < 8; ++mi)
    #pragma unroll
    for (int ni = 0; ni < 4; ++ni)
      #pragma unroll
      for (int rr = 0; rr < 4; ++rr) {
        int row = mtile * 256 + wr * 128 + mi * 16 + g * 4 + rr;
        int col = ntile * 256 + wc * 64 + ni * 16 + r;
        C[(size_t)row * N + col] = f2bf(acc[mi][ni][rr]);
      }
}

// ---------------- GEMM: C[M][N] = A[M][K] * Bt[N][K]^T (bf16 in, f32 acc) --
// 128x128 tile, 2-phase structure (used for the O projection).
template<int F32OUT>
__global__ __launch_bounds__(256)
void gemm_bt(const u16* __restrict__ A, const u16* __restrict__ Bt,
             void* __restrict__ C, int M, int N, int K) {
  const int tid = threadIdx.x;
  const int wave = tid >> 6, lane = tid & 63;
  const int mt = blockIdx.y, nt0 = blockIdx.x;
  __shared__ __align__(16) u16 ldsA[2][128 * 32];
  __shared__ __align__(16) u16 ldsB[2][128 * 32];

  const int wm = (wave >> 1) * 64, wn = (wave & 1) * 64;
  const int r = lane & 15, g = lane >> 4;

  f32x4 acc[4][4];
  const f32x4 z4 = {0.f, 0.f, 0.f, 0.f};
  #pragma unroll
  for (int i = 0; i < 4; ++i)
    #pragma unroll
    for (int j = 0; j < 4; ++j) acc[i][j] = z4;

  const u16* Abase = A + (size_t)mt * 128 * K;
  const u16* Bbase = Bt + (size_t)nt0 * 128 * K;

  auto stage = [&](u16* dst, const u16* src, int kb) {
    #pragma unroll
    for (int c = 0; c < 2; ++c) {
      int chunk = wave * 128 + c * 64 + lane;
      int row = chunk >> 2;
      int colb = (chunk & 3) << 4;
      int scolb = colb ^ (((row >> 1) & 3) << 4);
      gload_lds16(src + (size_t)row * K + kb + (scolb >> 1),
                  dst + (wave * 128 + c * 64) * 8);
    }
  };

  const int nk = K >> 5;
  stage(ldsA[0], Abase, 0);
  stage(ldsB[0], Bbase, 0);
  __syncthreads();

  for (int kt = 0; kt < nk; ++kt) {
    const int cur = kt & 1;
    if (kt + 1 < nk) {
      stage(ldsA[cur ^ 1], Abase, (kt + 1) << 5);
      stage(ldsB[cur ^ 1], Bbase, (kt + 1) << 5);
    }
    bf16x8 af[4], bfr[4];
    #pragma unroll
    for (int mi = 0; mi < 4; ++mi) {
      int row = wm + mi * 16 + r;
      int off = row * 32 + (((g << 4) ^ (((row >> 1) & 3) << 4)) >> 1);
      af[mi] = *(const bf16x8*)&ldsA[cur][off];
    }
    #pragma unroll
    for (int ni = 0; ni < 4; ++ni) {
      int row = wn + ni * 16 + r;
      int off = row * 32 + (((g << 4) ^ (((row >> 1) & 3) << 4)) >> 1);
      bfr[ni] = *(const bf16x8*)&ldsB[cur][off];
    }
    #pragma unroll
    for (int mi = 0; mi < 4; ++mi)
      #pragma unroll
      for (int ni = 0; ni < 4; ++ni)
        acc[mi][ni] = mfma16(af[mi], bfr[ni], acc[mi][ni]);
    __syncthreads();
  }

  #pragma unroll
  for (int mi = 0; mi < 4; ++mi)
    #pragma unroll
    for (int ni = 0; ni < 4; ++ni)
      #pragma unroll
      for (int rr = 0; rr < 4; ++rr) {
        int row = mt * 128 + wm + mi * 16 + g * 4 + rr;
        int col = nt0 * 128 + wn + ni * 16 + r;
        float v = acc[mi][ni][rr];
        if (F32OUT) ((float*)C)[(size_t)row * N + col] = v;
        else        ((u16*)C)[(size_t)row * N + col] = f2bf(v);
      }
}

// ---------------- RoPE + rearrange: src[NTOK][ldsrc] -> dst[B][H][SEQ][DH] --
__global__ __launch_bounds__(256)
void rope_rearrange(const u16* __restrict__ src, int ldsrc,
                    const float* __restrict__ cosT, const float* __restrict__ sinT,
                    u16* __restrict__ dst, float scale) {
  int id = blockIdx.x * 256 + threadIdx.x;
  int d2 = id & 63;
  int hh = (id >> 6) & 15;
  int tok = id >> 10;
  int n = tok & (SEQ - 1);
  int b = tok >> 11;
  const u16* s = src + (size_t)tok * ldsrc + hh * DH;
  float t1 = bf2f(s[d2]), t2 = bf2f(s[d2 + 64]);
  float c1 = cosT[n * DH + d2], c2 = cosT[n * DH + d2 + 64];
  float s1 = sinT[n * DH + d2], s2 = sinT[n * DH + d2 + 64];
  u16* dp = dst + ((size_t)(b * HEADS + hh) * SEQ + n) * DH;
  dp[d2]      = f2bf((t1 * c1 - t2 * s1) * scale);
  dp[d2 + 64] = f2bf((t2 * c2 + t1 * s2) * scale);
}

// ---------------- V transpose: v0[NTOK][ld] -> vT[B][H][DH][SEQ] ----------
__global__ __launch_bounds__(256)
void transp_v(const u16* __restrict__ v0, int ld, u16* __restrict__ vTo) {
  __shared__ __align__(16) u16 t[32][136];
  const int id = blockIdx.x;
  const int ntile = id & 63;
  const int hh = (id >> 6) & 15;
  const int b = id >> 10;
  const int tid = threadIdx.x;
  const int n0 = ntile * 32;
  #pragma unroll
  for (int it = 0; it < 2; ++it) {
    int chunk = it * 256 + tid;
    int nr = chunk >> 4, dc = chunk & 15;
    const u16* src = v0 + (size_t)(b * SEQ + n0 + nr) * ld + hh * DH + dc * 8;
    *(uint4*)&t[nr][dc * 8] = *(const uint4*)src;
  }
  __syncthreads();
  int d = tid >> 1, nh = tid & 1;
  u16 tmp[16];
  #pragma unroll
  for (int j = 0; j < 16; ++j) tmp[j] = t[nh * 16 + j][d];
  u16* dst = vTo + ((size_t)(b * HEADS + hh) * DH + d) * SEQ + n0 + nh * 16;
  *(uint4*)&dst[0] = *(const uint4*)&tmp[0];
  *(uint4*)&dst[8] = *(const uint4*)&tmp[8];
}

// ---------------- flash attention (causal), pair-balanced + double-buffered -
__global__ __launch_bounds__(256)
void flash(const u16* __restrict__ qr, const u16* __restrict__ kr,
           const u16* __restrict__ vT, u16* __restrict__ attn) {
  const int hb = blockIdx.x;
  const int h = hb & 15, b = hb >> 4;
  const int pairi = blockIdx.y;
  const int tid = threadIdx.x, wave = tid >> 6, lane = tid & 63;
  const int r = lane & 15, g = lane >> 4;

  __shared__ __align__(16) u16 kT[2][64 * 128];
  __shared__ __align__(16) u16 vS[2][128 * 64];
  __shared__ __align__(16) u16 pS[4][16 * 64];

  const size_t headq = (size_t)(b * HEADS + h) * SEQ;
  const u16* kbase = kr + headq * DH;
  const u16* vbase = vT + (size_t)(b * HEADS + h) * DH * SEQ;

  auto stageKV = [&](int buf, int kt) {
    #pragma unroll
    for (int c = 0; c < 4; ++c) {
      int chunk = (wave * 4 + c) * 64 + lane;
      int row = chunk >> 4;
      int scolb = ((chunk & 15) << 4) ^ ((row & 7) << 4);
      gload_lds16(kbase + (size_t)(kt * 64 + row) * DH + (scolb >> 1),
                  kT[buf] + (wave * 4 + c) * 64 * 8);
    }
    #pragma unroll
    for (int c = 0; c < 4; ++c) {
      int chunk = (wave * 4 + c) * 64 + lane;
      int d = chunk >> 3;
      int sb = ((chunk & 7) << 4) ^ ((d & 7) << 4);
      gload_lds16(vbase + (size_t)d * SEQ + kt * 64 + (sb >> 1),
                  vS[buf] + (wave * 4 + c) * 64 * 8);
    }
  };

  const f32x4 z4 = {0.f, 0.f, 0.f, 0.f};

  #pragma unroll 1
  for (int pass = 0; pass < 2; ++pass) {
    const int qt = pass ? (31 - pairi) : pairi;
    const u16* qbase = qr + (headq + qt * 64 + wave * 16) * DH;

    bf16x8 qf[4];
    #pragma unroll
    for (int ks = 0; ks < 4; ++ks)
      qf[ks] = *(const bf16x8*)(qbase + r * DH + ks * 32 + g * 8);

    f32x4 o[8];
    #pragma unroll
    for (int i = 0; i < 8; ++i) o[i] = z4;
    float m[4], lsum[4];
    #pragma unroll
    for (int i = 0; i < 4; ++i) { m[i] = -3.0e38f; lsum[i] = 0.f; }

    const int nkv = qt + 1;
    stageKV(0, 0);
    __syncthreads();

    for (int kt = 0; kt < nkv; ++kt) {
      const int cur = kt & 1;
      if (kt + 1 < nkv) stageKV(cur ^ 1, kt + 1);

      f32x4 s[4];
      #pragma unroll
      for (int i = 0; i < 4; ++i) s[i] = z4;
      #pragma unroll
      for (int ks = 0; ks < 4; ++ks) {
        #pragma unroll
        for (int nt = 0; nt < 4; ++nt) {
          int row = nt * 16 + r;
          int off = row * 128 + (((ks * 64 + g * 16) ^ ((row & 7) << 4)) >> 1);
          bf16x8 kf = *(const bf16x8*)&kT[cur][off];
          s[nt] = mfma16(qf[ks], kf, s[nt]);
        }
      }

      if (kt == qt) {
        #pragma unroll
        for (int nt = 0; nt < 4; ++nt)
          #pragma unroll
          for (int rr = 0; rr < 4; ++rr) {
            int colg = nt * 16 + r;
            int rowg = wave * 16 + g * 4 + rr;
            if (colg > rowg) s[nt][rr] = -1e30f;
          }
      }

      float mnew[4], alpha[4], rs[4];
      #pragma unroll
      for (int rr = 0; rr < 4; ++rr) {
        float mx = fmaxf(fmaxf(s[0][rr], s[1][rr]), fmaxf(s[2][rr], s[3][rr]));
        #pragma unroll
        for (int off = 1; off < 16; off <<= 1)
          mx = fmaxf(mx, __shfl_xor(mx, off));
        mnew[rr] = fmaxf(m[rr], mx);
        alpha[rr] = __expf(m[rr] - mnew[rr]);
        m[rr] = mnew[rr];
        rs[rr] = 0.f;
      }
      #pragma unroll
      for (int nt = 0; nt < 4; ++nt)
        #pragma unroll
        for (int rr = 0; rr < 4; ++rr) {
          float p = __expf(s[nt][rr] - mnew[rr]);
          rs[rr] += p;
          int prow = g * 4 + rr;
          int colb = (nt * 16 + r) << 1;
          int off = prow * 64 + ((colb ^ ((prow & 7) << 4)) >> 1);
          pS[wave][off] = f2bf(p);
        }
      #pragma unroll
      for (int rr = 0; rr < 4; ++rr) {
        float tsum = rs[rr];
        #pragma unroll
        for (int off = 1; off < 16; off <<= 1) tsum += __shfl_xor(tsum, off);
        lsum[rr] = lsum[rr] * alpha[rr] + tsum;
      }
      #pragma unroll
      for (int dt = 0; dt < 8; ++dt)
        #pragma unroll
        for (int rr = 0; rr < 4; ++rr)
          o[dt][rr] *= alpha[rr];

      #pragma unroll
      for (int ks = 0; ks < 2; ++ks) {
        int poff = r * 64 + (((ks * 64 + g * 16) ^ ((r & 7) << 4)) >> 1);
        bf16x8 pf = *(const bf16x8*)&pS[wave][poff];
        #pragma unroll
        for (int dt = 0; dt < 8; ++dt) {
          int vrow = dt * 16 + r;
          int voff = vrow * 64 + (((ks * 64 + g * 16) ^ ((vrow & 7) << 4)) >> 1);
          bf16x8 vf = *(const bf16x8*)&vS[cur][voff];
          o[dt] = mfma16(pf, vf, o[dt]);
        }
      }
      __syncthreads();
    }

    #pragma unroll
    for (int dt = 0; dt < 8; ++dt)
      #pragma unroll
      for (int rr = 0; rr < 4; ++rr) {
        int rowg = qt * 64 + wave * 16 + g * 4 + rr;
        attn[((size_t)b * SEQ + rowg) * INNER + h * DH + dt * 16 + r] =
            f2bf(o[dt][rr] / lsum[rr]);
      }
  }
}

// ---------------- host ----------------
extern "C" void kernel_launch(void* const* d_in, const int* in_sizes, int n_in,
                              void* d_out, int out_size, void* d_ws, size_t ws_size,
                              hipStream_t stream) {
  const float* x   = (const float*)d_in[0];
  const float* rot = (const float*)d_in[1];
  const float* g   = (const float*)d_in[2];
  const float* Wq  = (const float*)d_in[3];
  const float* Wkv = (const float*)d_in[4];
  const float* Wo  = (const float*)d_in[5];

  char* ws = (char*)d_ws;
  size_t off = 0;
  auto alloc = [&](size_t bytes) {
    char* p = ws + off;
    off += (bytes + 255) & ~(size_t)255;
    return p;
  };
  u16*   WqkvT = (u16*)alloc((size_t)6144 * 2048 * 2);  // q rows 0-2047, k 2048-4095, v 4096-6143
  u16*   WoT   = (u16*)alloc((size_t)2048 * 2048 * 2);
  float* cosT  = (float*)alloc((size_t)2048 * 128 * 4);
  float* sinT  = (float*)alloc((size_t)2048 * 128 * 4);
  u16*   xn    = (u16*)alloc((size_t)4096 * 2048 * 2);
  u16*   qkv   = (u16*)alloc((size_t)4096 * 6144 * 2);
  u16*   qr    = (u16*)alloc((size_t)4096 * 2048 * 2);
  // region reuse (dependency-checked against launch order below):
  u16* kr   = WqkvT;  // WqkvT (25.2MB >= 16.8MB) dead after QKV GEMM
  u16* vt   = xn;     // xn dead after QKV GEMM
  u16* attn = qkv;    // qkv dead after rope_q + rope_k + transp_v

  transpose_cast<<<dim3(64 * 64),  256, 0, stream>>>(Wq,  WqkvT,               2048, 2048);
  transpose_cast<<<dim3(64 * 128), 256, 0, stream>>>(Wkv, WqkvT + 2048 * 2048, 2048, 4096);
  transpose_cast<<<dim3(64 * 64),  256, 0, stream>>>(Wo,  WoT,                 2048, 2048);
  build_tables<<<dim3(2048 * 128 / 256), 256, 0, stream>>>(rot, cosT, sinT);
  rmsnorm_k<<<dim3(4096), 256, 0, stream>>>(x, g, xn);
  gemm_qkv<<<dim3(384), 512, 0, stream>>>(xn, WqkvT, qkv, 4096, 6144, 2048);
  rope_rearrange<<<dim3(16384), 256, 0, stream>>>(qkv,        6144, cosT, sinT, qr, 0.08838834764831845f);
  rope_rearrange<<<dim3(16384), 256, 0, stream>>>(qkv + 2048, 6144, cosT, sinT, kr, 1.0f);
  transp_v<<<dim3(2048), 256, 0, stream>>>(qkv + 4096, 6144, vt);
  flash<<<dim3(32, 16), 256, 0, stream>>>(qr, kr, vt, attn);
  gemm_bt<1><<<dim3(16, 32), 256, 0, stream>>>(attn, WoT, (float*)d_out, 4096, 2048, 2048);
}